// Round 1
// baseline (212.191 us; speedup 1.0000x reference)
//
#include <hip/hip_runtime.h>

// out[i] = cos(x[i,0] + weights[0]); x is [N][2] f32 interleaved, out is [N] f32.
// Memory-bound: ~201 MB traffic. Each thread handles 2 samples via one float4
// load (coalesced 16B/lane) and one float2 store (8B/lane).

__global__ __launch_bounds__(256) void hybridqnn_cos_kernel(
    const float4* __restrict__ x4,   // pairs of samples: (x0,x1,x0',x1')
    const float* __restrict__ w,     // weights[2]; only w[0] used
    float2* __restrict__ out2,
    int n4)                          // number of float4 elements = N/2
{
    const float w0 = w[0];
    int idx = blockIdx.x * blockDim.x + threadIdx.x;
    int stride = gridDim.x * blockDim.x;
    for (int i = idx; i < n4; i += stride) {
        float4 v = x4[i];
        float2 o;
        o.x = __cosf(v.x + w0);
        o.y = __cosf(v.z + w0);
        out2[i] = o;
    }
}

extern "C" void kernel_launch(void* const* d_in, const int* in_sizes, int n_in,
                              void* d_out, int out_size, void* d_ws, size_t ws_size,
                              hipStream_t stream) {
    const float4* x4 = (const float4*)d_in[0];   // x: (N,2) f32
    const float*  w  = (const float*)d_in[1];    // weights: (2,) f32
    float2* out2 = (float2*)d_out;               // out: (N,) f32

    int n  = in_sizes[0] / 2;   // N samples
    int n4 = n / 2;             // float4 elements (N is a power of two, even)

    int block = 256;
    int grid  = 2048;           // grid-stride; 8 blocks/CU on 256 CUs
    int work  = (n4 + block - 1) / block;
    if (work < grid) grid = work;

    hybridqnn_cos_kernel<<<grid, block, 0, stream>>>(x4, w, out2, n4);
}

// Round 3
// 210.257 us; speedup vs baseline: 1.0092x; 1.0092x over previous
//
#include <hip/hip_runtime.h>

// out[i] = cos(x[i,0] + weights[0]); x is [N][2] f32 interleaved, out is [N] f32.
// Traffic floor: 128 MiB read (x columns interleaved -> both fetched) +
// 64 MiB write = 192 MiB. 4 samples/thread: two float4 loads (32 B/lane),
// one nontemporal 16B store (native clang vector — HIP float4 is a struct
// and the builtin rejects it).

typedef float fvec4 __attribute__((ext_vector_type(4)));

__global__ __launch_bounds__(256) void hybridqnn_cos_kernel(
    const float4* __restrict__ x4,   // (x0,x1,x0',x1') sample pairs
    const float* __restrict__ w,     // weights[2]; only w[0] used
    fvec4* __restrict__ out4,
    int nOut4)                       // N/4 output vec4 elements
{
    const float w0 = w[0];
    int idx = blockIdx.x * blockDim.x + threadIdx.x;
    int stride = gridDim.x * blockDim.x;
    for (int i = idx; i < nOut4; i += stride) {
        float4 a = x4[2 * i];
        float4 b = x4[2 * i + 1];
        fvec4 o;
        o.x = __cosf(a.x + w0);
        o.y = __cosf(a.z + w0);
        o.z = __cosf(b.x + w0);
        o.w = __cosf(b.z + w0);
        __builtin_nontemporal_store(o, &out4[i]);
    }
}

extern "C" void kernel_launch(void* const* d_in, const int* in_sizes, int n_in,
                              void* d_out, int out_size, void* d_ws, size_t ws_size,
                              hipStream_t stream) {
    const float4* x4 = (const float4*)d_in[0];   // x: (N,2) f32
    const float*  w  = (const float*)d_in[1];    // weights: (2,) f32
    fvec4* out4 = (fvec4*)d_out;                 // out: (N,) f32

    int n     = in_sizes[0] / 2;  // N samples
    int nOut4 = n / 4;            // N = 2^24, divisible by 4

    int block = 256;
    int grid  = 2048;             // 8 blocks/CU on 256 CUs, grid-stride
    int work  = (nOut4 + block - 1) / block;
    if (work < grid) grid = work;

    hybridqnn_cos_kernel<<<grid, block, 0, stream>>>(x4, w, out4, nOut4);
}